// Round 2
// baseline (131.955 us; speedup 1.0000x reference)
//
#include <hip/hip_runtime.h>
#include <stdint.h>

constexpr int kB = 16;
constexpr int kN = 1024;
constexpr int kE = 16;

// ---------------- DPP helpers (16-lane groups) ----------------
template<int CTRL>
__device__ __forceinline__ float dppv(float v) {
    int y = __builtin_amdgcn_update_dpp(0, __float_as_int(v), CTRL, 0xF, 0xF, true);
    return __int_as_float(y);
}
template<int CTRL>
__device__ __forceinline__ float dpp_add(float x) { return x + dppv<CTRL>(x); }

// all-reduce sum over the 16-lane row (rotate-reduce, pure DPP)
__device__ __forceinline__ float rsum16(float x) {
    x = dpp_add<0x121>(x);   // row_ror:1
    x = dpp_add<0x122>(x);   // row_ror:2
    x = dpp_add<0x124>(x);   // row_ror:4
    x = dpp_add<0x128>(x);   // row_ror:8
    return x;
}

__device__ __forceinline__ uint32_t pack_bf16(float lo, float hi) {
    uint32_t ul = (__float_as_uint(lo) + 0x8000u) >> 16;
    uint32_t uh = (__float_as_uint(hi) + 0x8000u) & 0xFFFF0000u;
    return uh | ul;
}

// ---------------------------------------------------------------------------
// apply_S: Y[b,n,:] = softmax_row(relu(emb[b] @ emb[b]^T)) @ V[b]
// grid = B*(N/64) = 256 blocks, 256 threads. 64 rows/block.
// Thread: rg = tid>>4 (4 rows each), s = tid&15 (m-subset).
// relu>=0 and |dot| <= ~70 => exp without max-subtraction safe in fp32.
// Logits exact fp32; only V is bf16-rounded in LDS (~0.4% rel on avg).
// ---------------------------------------------------------------------------
__global__ __launch_bounds__(256, 1) void apply_S(
    const float* __restrict__ emb,   // [B,N,16]
    const float* __restrict__ V,     // [B,N,32]
    float* __restrict__ Y)           // [B,N,32]
{
    __shared__ alignas(16) float    emb_s[64][20];  // fp32 keys, pad 20 (80B rows)
    __shared__ alignas(16) uint32_t v_s[64][20];    // bf16x2 values, 16 used + pad

    const int tid = threadIdx.x;
    const int s   = tid & 15;
    const int rg  = tid >> 4;                 // 0..15
    const int b   = blockIdx.x >> 4;
    const int row_base = (blockIdx.x & 15) << 6;

    const float* embB = emb + (size_t)b * kN * kE;
    const float* vB   = V   + (size_t)b * kN * 32;

    // 4 query rows in registers
    float en[4][16];
    #pragma unroll
    for (int j = 0; j < 4; ++j) {
        const float4* p = (const float4*)(embB + (size_t)(row_base + rg * 4 + j) * kE);
        #pragma unroll
        for (int q = 0; q < 4; ++q) {
            float4 a = p[q];
            en[j][4*q+0] = a.x; en[j][4*q+1] = a.y; en[j][4*q+2] = a.z; en[j][4*q+3] = a.w;
        }
    }

    float acc[4][32];
    #pragma unroll
    for (int j = 0; j < 4; ++j)
        #pragma unroll
        for (int d = 0; d < 32; ++d) acc[j][d] = 0.f;
    float L[4] = {0.f, 0.f, 0.f, 0.f};

    // staging assignments
    const int er = tid >> 2, ec4 = (tid & 3) << 2;     // emb: 1 float4
    const int vr = tid >> 3, vd4 = tid & 7;            // v: 2 float4 (q=0,1)

    float4 ebuf, vbuf0, vbuf1;
    ebuf  = *(const float4*)(embB + (size_t)er * 16 + ec4);
    vbuf0 = *(const float4*)(vB + (size_t)vr * 32 + vd4 * 4);
    vbuf1 = *(const float4*)(vB + (size_t)(32 + vr) * 32 + vd4 * 4);

    for (int t = 0; t < 16; ++t) {
        __syncthreads();
        // write staged tile
        *(float4*)(&emb_s[er][ec4]) = ebuf;
        {
            uint2 u0 = make_uint2(pack_bf16(vbuf0.x, vbuf0.y), pack_bf16(vbuf0.z, vbuf0.w));
            uint2 u1 = make_uint2(pack_bf16(vbuf1.x, vbuf1.y), pack_bf16(vbuf1.z, vbuf1.w));
            *(uint2*)(&v_s[vr][vd4 * 2])      = u0;
            *(uint2*)(&v_s[32 + vr][vd4 * 2]) = u1;
        }
        __syncthreads();
        // prefetch next tile (in flight during compute)
        if (t < 15) {
            int m0 = (t + 1) << 6;
            ebuf  = *(const float4*)(embB + (size_t)(m0 + er) * 16 + ec4);
            vbuf0 = *(const float4*)(vB + (size_t)(m0 + vr) * 32 + vd4 * 4);
            vbuf1 = *(const float4*)(vB + (size_t)(m0 + 32 + vr) * 32 + vd4 * 4);
        }

        #pragma unroll
        for (int mj = 0; mj < 4; ++mj) {
            const int ml = (mj << 4) + s;
            float e16[16];
            #pragma unroll
            for (int q = 0; q < 4; ++q) {
                float4 a = *(const float4*)(&emb_s[ml][q * 4]);
                e16[4*q+0] = a.x; e16[4*q+1] = a.y; e16[4*q+2] = a.z; e16[4*q+3] = a.w;
            }
            uint4 vv[4];
            #pragma unroll
            for (int q = 0; q < 4; ++q) vv[q] = *(const uint4*)(&v_s[ml][q * 4]);

            float p[4];
            #pragma unroll
            for (int j = 0; j < 4; ++j) {
                float d = 0.f;
                #pragma unroll
                for (int c = 0; c < 16; ++c) d = fmaf(en[j][c], e16[c], d);
                p[j] = __expf(fmaxf(d, 0.f));
                L[j] += p[j];
            }
            #pragma unroll
            for (int q = 0; q < 4; ++q) {
                #pragma unroll
                for (int u = 0; u < 4; ++u) {
                    uint32_t w = ((const uint32_t*)&vv[q])[u];
                    float vlo = __uint_as_float(w << 16);
                    float vhi = __uint_as_float(w & 0xFFFF0000u);
                    const int d0 = q * 8 + u * 2;
                    #pragma unroll
                    for (int j = 0; j < 4; ++j) {
                        acc[j][d0]     = fmaf(p[j], vlo, acc[j][d0]);
                        acc[j][d0 + 1] = fmaf(p[j], vhi, acc[j][d0 + 1]);
                    }
                }
            }
        }
    }

    // ---- reduce-scatter over the 16 m-subset lanes ----
    // lane s ends with d = 2s, 2s+1 sums; no runtime register indexing.
    float* yB = Y + (size_t)b * kN * 32;
    #pragma unroll
    for (int j = 0; j < 4; ++j) {
        float Lr = rsum16(L[j]);
        float t32[32];
        #pragma unroll
        for (int k = 0; k < 32; ++k) t32[k] = acc[j][k] + dppv<0x128>(acc[j][k]); // xor8
        const bool b4 = (s & 8);
        float y16[16];
        #pragma unroll
        for (int i = 0; i < 16; ++i) y16[i] = b4 ? t32[16 + i] : t32[i];
        #pragma unroll
        for (int i = 0; i < 16; ++i) y16[i] = y16[i] + dppv<0x4E>(y16[i]);        // xor2
        const bool b2 = (s & 2);
        float z8[8];
        #pragma unroll
        for (int i = 0; i < 8; ++i) {
            const int b3i = i >> 2, rest = i & 3;
            z8[i] = b2 ? y16[b3i * 8 + 4 + rest] : y16[b3i * 8 + rest];
        }
        #pragma unroll
        for (int i = 0; i < 8; ++i) z8[i] = z8[i] + dppv<0xB1>(z8[i]);            // xor1
        const bool b1 = (s & 1);
        float u4[4];
        #pragma unroll
        for (int i = 0; i < 4; ++i) {
            const int b3i = i >> 1, b0 = i & 1;
            u4[i] = b1 ? z8[b3i * 4 + 2 + b0] : z8[b3i * 4 + b0];
        }
        #pragma unroll
        for (int i = 0; i < 4; ++i) u4[i] = u4[i] + __shfl_xor(u4[i], 4);         // xor4
        const bool b3 = (s & 4);
        const float r0 = b3 ? u4[2] : u4[0];
        const float r1 = b3 ? u4[3] : u4[1];

        const float iL = 1.f / Lr;
        *(float2*)(yB + (size_t)(row_base + rg * 4 + j) * 32 + 2 * s) =
            make_float2(r0 * iL, r1 * iL);
    }
}

// ---------------------------------------------------------------------------
// w_transpose: W[16][3][32][32] -> wt[96][32][20] (pad 20, e-chunk XOR swizzle)
// wt[kk][o][ (j^sw(o))*4 + (e&3) ] = W[e][kk/32][kk%32][o],  j = e>>2
// ---------------------------------------------------------------------------
__global__ void w_transpose(const float* __restrict__ W, float* __restrict__ wt) {
    int idx = blockIdx.x * 256 + threadIdx.x;      // 0 .. 61439
    int kk  = idx / 640;
    int rem = idx - kk * 640;
    int o   = rem / 20;
    int c   = rem - o * 20;
    float v = 0.f;
    if (c < 16) {
        int sw = (o + (o >> 3)) & 3;
        int e  = (((c >> 2) ^ sw) << 2) | (c & 3);
        v = W[(size_t)e * 3072 + (size_t)kk * 32 + o];
    }
    wt[idx] = v;
}

// ---------------------------------------------------------------------------
// final_gemm: out[n,o] = sum_e s[n,e]*(bias[e,o] + sum_ki XG[n,ki]*W[e,ki,o])
// 64 rows/block, grid 256. Thread = (o = tid&31, rg = tid>>5 -> 8 rows),
// acc[8 rows][16 e]. W chunks of 24 kk staged linearly from swizzled wt.
// ---------------------------------------------------------------------------
__global__ __launch_bounds__(256, 1) void final_gemm(
    const float* __restrict__ x,      // [B*N,32]
    const float* __restrict__ y1,
    const float* __restrict__ y2,
    const float* __restrict__ stock,  // [B*N,16]
    const float* __restrict__ wt,     // [96][32][20] swizzled
    const float* __restrict__ bias,   // [16,32]
    float* __restrict__ out)          // [B*N,32]
{
    __shared__ alignas(16) float w_s[24 * 32 * 20];  // 61440 B
    __shared__ alignas(16) float xg_t[96 * 68];      // 26112 B (transposed, pad 68)
    __shared__ alignas(16) float s_s[64 * 16];       // 4096 B

    const int tid  = threadIdx.x;
    const int o    = tid & 31;
    const int rg   = tid >> 5;                 // 0..7
    const int row0 = blockIdx.x << 6;
    const int sw   = (o + (o >> 3)) & 3;

    // stage XG transposed: xg_t[ki][r]
    #pragma unroll
    for (int q = 0; q < 2; ++q) {
        int f = q * 256 + tid;
        int r = f >> 3, i4 = (f & 7) << 2;
        size_t g = (size_t)(row0 + r) * 32 + i4;
        float4 xv  = *(const float4*)(x + g);
        float4 y1v = *(const float4*)(y1 + g);
        float4 y2v = *(const float4*)(y2 + g);
        #pragma unroll
        for (int jj = 0; jj < 4; ++jj) {
            float xs  = ((const float*)&xv)[jj];
            float y1s = ((const float*)&y1v)[jj];
            float y2s = ((const float*)&y2v)[jj];
            int i = i4 + jj;
            xg_t[i * 68 + r]        = xs;
            xg_t[(32 + i) * 68 + r] = y1s;
            xg_t[(64 + i) * 68 + r] = 2.f * y2s - xs;
        }
    }
    {
        int r = tid >> 2, e4 = (tid & 3) << 2;
        *(float4*)(&s_s[r * 16 + e4]) = *(const float4*)(stock + (size_t)(row0 + r) * 16 + e4);
    }

    float bv[16];
    #pragma unroll
    for (int e = 0; e < 16; ++e) bv[e] = bias[e * 32 + o];

    float acc[8][16];
    #pragma unroll
    for (int r = 0; r < 8; ++r)
        #pragma unroll
        for (int e = 0; e < 16; ++e) acc[r][e] = 0.f;

    for (int ch = 0; ch < 4; ++ch) {
        __syncthreads();
        const float4* src = (const float4*)(wt + ch * 15360);
        float4* dst = (float4*)w_s;
        #pragma unroll
        for (int q = 0; q < 15; ++q)
            dst[q * 256 + tid] = src[q * 256 + tid];
        __syncthreads();

        for (int kl = 0; kl < 24; ++kl) {
            const int kg = ch * 24 + kl;
            float xr[8];
            *(float4*)&xr[0] = *(const float4*)(xg_t + kg * 68 + rg * 8);
            *(float4*)&xr[4] = *(const float4*)(xg_t + kg * 68 + rg * 8 + 4);
            const float* wb = w_s + (kl * 32 + o) * 20;
            float we[16];
            #pragma unroll
            for (int j = 0; j < 4; ++j)
                *(float4*)&we[4 * j] = *(const float4*)(wb + ((j ^ sw) << 2));
            #pragma unroll
            for (int e = 0; e < 16; ++e)
                #pragma unroll
                for (int r = 0; r < 8; ++r)
                    acc[r][e] = fmaf(xr[r], we[e], acc[r][e]);
        }
    }

    #pragma unroll
    for (int r = 0; r < 8; ++r) {
        const int row = rg * 8 + r;
        float sum = 0.f;
        #pragma unroll
        for (int e = 0; e < 16; ++e)
            sum = fmaf(s_s[row * 16 + e], acc[r][e] + bv[e], sum);
        out[(size_t)(row0 + row) * 32 + o] = sum;
    }
}

extern "C" void kernel_launch(void* const* d_in, const int* in_sizes, int n_in,
                              void* d_out, int out_size, void* d_ws, size_t ws_size,
                              hipStream_t stream) {
    const float* x     = (const float*)d_in[0];
    const float* aemb  = (const float*)d_in[1];
    const float* stock = (const float*)d_in[2];
    const float* Wp    = (const float*)d_in[3];
    const float* bias  = (const float*)d_in[4];
    float* out = (float*)d_out;

    float* y1 = (float*)d_ws;
    float* y2 = y1 + (size_t)kB * kN * 32;
    float* wt = y2 + (size_t)kB * kN * 32;

    w_transpose<<<dim3(240), dim3(256), 0, stream>>>(Wp, wt);
    apply_S<<<dim3(kB * (kN / 64)), dim3(256), 0, stream>>>(aemb, x,  y1);
    apply_S<<<dim3(kB * (kN / 64)), dim3(256), 0, stream>>>(aemb, y1, y2);
    final_gemm<<<dim3((kB * kN) / 64), dim3(256), 0, stream>>>(x, y1, y2, stock, wt, bias, out);
}

// Round 3
// 64.861 us; speedup vs baseline: 2.0344x; 2.0344x over previous
//
#include <hip/hip_runtime.h>
#include <stdint.h>

typedef __bf16 bf16x8 __attribute__((ext_vector_type(8)));
typedef __bf16 bf16x4 __attribute__((ext_vector_type(4)));
typedef float  f32x16 __attribute__((ext_vector_type(16)));

constexpr int kB = 16;
constexpr int kN = 1024;
constexpr int kE = 16;

// ---------------------------------------------------------------------------
// k_es: emb [B*N,16] fp32 -> es [B*N][32] bf16 rows = [16 ehi | 16 elo]
// hi/lo split: e = ehi + elo exactly to ~2^-17 rel.
// ---------------------------------------------------------------------------
__global__ __launch_bounds__(256) void k_es(const float* __restrict__ emb,
                                            __bf16* __restrict__ es) {
    int c = blockIdx.x * 256 + threadIdx.x;     // 16B chunk id, 0..65535
    int row = c >> 2, seg = c & 3;
    float4 v = *(const float4*)(emb + (size_t)c * 4);
    float f[4] = {v.x, v.y, v.z, v.w};
    bf16x4 hi, lo;
    #pragma unroll
    for (int i = 0; i < 4; ++i) {
        __bf16 h = (__bf16)f[i];
        hi[i] = h;
        lo[i] = (__bf16)(f[i] - (float)h);
    }
    __bf16* r = es + (size_t)row * 32;
    *(bf16x4*)(r + seg * 4)      = hi;
    *(bf16x4*)(r + 16 + seg * 4) = lo;
}

// ---------------------------------------------------------------------------
// k_tr: src [B,N,32] fp32 -> vt [B][plane(hi/lo)][d=32][N] bf16 (transposed split)
// grid 256 (b, 64-row tile), 256 threads.
// ---------------------------------------------------------------------------
__global__ __launch_bounds__(256) void k_tr(const float* __restrict__ src,
                                            __bf16* __restrict__ vt) {
    __shared__ float ls[64 * 33];
    const int t = threadIdx.x;
    const int b = blockIdx.x >> 4, n0 = (blockIdx.x & 15) << 6;
    const float* sB = src + ((size_t)b * kN + n0) * 32;
    #pragma unroll
    for (int it = 0; it < 2; ++it) {
        int f = it * 256 + t;
        int row = f >> 3, q8 = f & 7;
        float4 v = *(const float4*)(sB + (size_t)row * 32 + q8 * 4);
        ls[row * 33 + q8 * 4 + 0] = v.x;
        ls[row * 33 + q8 * 4 + 1] = v.y;
        ls[row * 33 + q8 * 4 + 2] = v.z;
        ls[row * 33 + q8 * 4 + 3] = v.w;
    }
    __syncthreads();
    const int p = t >> 7, d = (t >> 2) & 31, ng = t & 3;
    bf16x8 o0, o1;
    #pragma unroll
    for (int i = 0; i < 16; ++i) {
        float v = ls[(ng * 16 + i) * 33 + d];
        __bf16 h = (__bf16)v;
        __bf16 o = (p == 0) ? h : (__bf16)(v - (float)h);
        if (i < 8) o0[i] = o; else o1[i - 8] = o;
    }
    __bf16* dp = vt + (size_t)b * 65536 + (size_t)p * 32768 + (size_t)d * 1024 + n0 + ng * 16;
    *(bf16x8*)dp       = o0;
    *(bf16x8*)(dp + 8) = o1;
}

// ---------------------------------------------------------------------------
// apply_mfma: Y[b,q,:] = softmax_row(relu(E E^T)) @ V  via bf16 MFMA 32x32x16.
// grid = B*(N/32) = 512 blocks, 256 threads (4 waves). Block = 32 q-rows.
// Waves split kk; per chunk of 256 kk staged in LDS, wave w does 64 kk.
// QK: 4 cross-term MFMAs (hi/lo exact); PV: P(bf16) x (v_hi,v_lo).
// Relies only on verified C/D layout + A/B k-order consistency.
// ---------------------------------------------------------------------------
__global__ __launch_bounds__(256, 2) void apply_mfma(
    const __bf16* __restrict__ es,   // [B][1024][32]
    const __bf16* __restrict__ vt,   // [B][2][32][1024]
    float* __restrict__ Y)           // [B,N,32]
{
    __shared__ __bf16 es_s[256 * 36];     // rows padded to 72B (2-way free)
    __shared__ __bf16 vt_s[2 * 32 * 260]; // rows padded to 520B (2-way free)
    __shared__ float  ps[4 * 32 * 33];
    __shared__ float  Ls[4 * 32];

    const int tid = threadIdx.x;
    const int w = tid >> 6, l = tid & 63;
    const int q = l & 31, h = l >> 5;
    const int b = blockIdx.x >> 5, q0 = (blockIdx.x & 31) << 5;

    const __bf16* esB = es + (size_t)b * 32768;
    const __bf16* vtB = vt + (size_t)b * 65536;

    // Q-side B-fragments (loaded once, from global; 16B aligned)
    const __bf16* qr = esB + (size_t)(q0 + q) * 32;
    bf16x8 bhi = *(const bf16x8*)(qr + 8 * h);
    bf16x8 blo = *(const bf16x8*)(qr + 16 + 8 * h);

    f32x16 acc = {};
    float Lp = 0.f;

    for (int ch = 0; ch < 4; ++ch) {
        __syncthreads();
        // stage es chunk (256 rows x 32 elems), coalesced 16B loads
        #pragma unroll
        for (int i = 0; i < 4; ++i) {
            int f = i * 256 + tid;
            int rl = f >> 2, seg = f & 3;
            bf16x8 v = *(const bf16x8*)(esB + (size_t)(ch * 256 + rl) * 32 + seg * 8);
            bf16x4 v0, v1;
            #pragma unroll
            for (int j = 0; j < 4; ++j) { v0[j] = v[j]; v1[j] = v[4 + j]; }
            *(bf16x4*)(es_s + rl * 36 + seg * 8)     = v0;
            *(bf16x4*)(es_s + rl * 36 + seg * 8 + 4) = v1;
        }
        // stage vt chunk (2 planes x 32 d x 256 kk)
        #pragma unroll
        for (int i = 0; i < 8; ++i) {
            int f = i * 256 + tid;
            int r = f >> 5, c16 = f & 31;
            bf16x8 v = *(const bf16x8*)(vtB + (size_t)r * 1024 + ch * 256 + c16 * 8);
            bf16x4 v0, v1;
            #pragma unroll
            for (int j = 0; j < 4; ++j) { v0[j] = v[j]; v1[j] = v[4 + j]; }
            *(bf16x4*)(vt_s + r * 260 + c16 * 8)     = v0;
            *(bf16x4*)(vt_s + r * 260 + c16 * 8 + 4) = v1;
        }
        __syncthreads();

        #pragma unroll
        for (int sub = 0; sub < 2; ++sub) {
            const int kbl = (w << 6) + (sub << 5);   // kk-local in chunk
            // QK A-fragments from es_s (rows kbl+q), split b64 (8B aligned)
            const __bf16* ar = es_s + (size_t)(kbl + q) * 36;
            bf16x4 a0 = *(const bf16x4*)(ar + 8 * h);
            bf16x4 a1 = *(const bf16x4*)(ar + 8 * h + 4);
            bf16x4 a2 = *(const bf16x4*)(ar + 16 + 8 * h);
            bf16x4 a3 = *(const bf16x4*)(ar + 16 + 8 * h + 4);
            bf16x8 ahi, alo;
            #pragma unroll
            for (int j = 0; j < 4; ++j) {
                ahi[j] = a0[j]; ahi[4 + j] = a1[j];
                alo[j] = a2[j]; alo[4 + j] = a3[j];
            }
            f32x16 S = {};
            S = __builtin_amdgcn_mfma_f32_32x32x16_bf16(ahi, bhi, S, 0, 0, 0);
            S = __builtin_amdgcn_mfma_f32_32x32x16_bf16(ahi, blo, S, 0, 0, 0);
            S = __builtin_amdgcn_mfma_f32_32x32x16_bf16(alo, bhi, S, 0, 0, 0);
            S = __builtin_amdgcn_mfma_f32_32x32x16_bf16(alo, blo, S, 0, 0, 0);

            float p[16];
            #pragma unroll
            for (int r = 0; r < 16; ++r) {
                p[r] = __expf(fmaxf(S[r], 0.f));
                Lp += p[r];
            }
            bf16x8 P0, P1;
            #pragma unroll
            for (int j = 0; j < 8; ++j) { P0[j] = (__bf16)p[j]; P1[j] = (__bf16)p[8 + j]; }

            // PV A-fragments from vt_s: lane index = d (= l&31), pi(h,j) offsets
            const __bf16* vh = vt_s + (size_t)q * 260;           // plane hi, d = l&31
            const __bf16* vl = vt_s + 32 * 260 + (size_t)q * 260; // plane lo
            bf16x4 w0a = *(const bf16x4*)(vh + kbl + 4 * h);
            bf16x4 w0b = *(const bf16x4*)(vh + kbl + 8 + 4 * h);
            bf16x4 w1a = *(const bf16x4*)(vh + kbl + 16 + 4 * h);
            bf16x4 w1b = *(const bf16x4*)(vh + kbl + 24 + 4 * h);
            bf16x4 w0c = *(const bf16x4*)(vl + kbl + 4 * h);
            bf16x4 w0d = *(const bf16x4*)(vl + kbl + 8 + 4 * h);
            bf16x4 w1c = *(const bf16x4*)(vl + kbl + 16 + 4 * h);
            bf16x4 w1d = *(const bf16x4*)(vl + kbl + 24 + 4 * h);
            bf16x8 A0h, A0l, A1h, A1l;
            #pragma unroll
            for (int j = 0; j < 4; ++j) {
                A0h[j] = w0a[j]; A0h[4 + j] = w0b[j];
                A0l[j] = w0c[j]; A0l[4 + j] = w0d[j];
                A1h[j] = w1a[j]; A1h[4 + j] = w1b[j];
                A1l[j] = w1c[j]; A1l[4 + j] = w1d[j];
            }
            acc = __builtin_amdgcn_mfma_f32_32x32x16_bf16(A0h, P0, acc, 0, 0, 0);
            acc = __builtin_amdgcn_mfma_f32_32x32x16_bf16(A0l, P0, acc, 0, 0, 0);
            acc = __builtin_amdgcn_mfma_f32_32x32x16_bf16(A1h, P1, acc, 0, 0, 0);
            acc = __builtin_amdgcn_mfma_f32_32x32x16_bf16(A1l, P1, acc, 0, 0, 0);
        }
    }

    // merge 4 wave-partials
    Lp += __shfl_xor(Lp, 32);
    #pragma unroll
    for (int r = 0; r < 16; ++r) {
        int d = (r & 3) + 8 * (r >> 2) + 4 * h;
        ps[w * 1056 + d * 33 + q] = acc[r];
    }
    if (l < 32) Ls[w * 32 + l] = Lp;
    __syncthreads();
    {
        const int qq = tid >> 3, dg = tid & 7;
        float iL = 1.f / (Ls[qq] + Ls[32 + qq] + Ls[64 + qq] + Ls[96 + qq]);
        float4 y;
        #pragma unroll
        for (int i = 0; i < 4; ++i) {
            int d = dg * 4 + i;
            ((float*)&y)[i] = (ps[d * 33 + qq] + ps[1056 + d * 33 + qq] +
                               ps[2112 + d * 33 + qq] + ps[3168 + d * 33 + qq]) * iL;
        }
        *(float4*)(Y + (size_t)(b * kN + q0 + qq) * 32 + dg * 4) = y;
    }
}

// ---------------------------------------------------------------------------
// w_transpose: W[16][3][32][32] -> wt[96][32][20] (pad 20, e-chunk XOR swizzle)
// ---------------------------------------------------------------------------
__global__ void w_transpose(const float* __restrict__ W, float* __restrict__ wt) {
    int idx = blockIdx.x * 256 + threadIdx.x;      // 0 .. 61439
    int kk  = idx / 640;
    int rem = idx - kk * 640;
    int o   = rem / 20;
    int c   = rem - o * 20;
    float v = 0.f;
    if (c < 16) {
        int sw = (o + (o >> 3)) & 3;
        int e  = (((c >> 2) ^ sw) << 2) | (c & 3);
        v = W[(size_t)e * 3072 + (size_t)kk * 32 + o];
    }
    wt[idx] = v;
}

// ---------------------------------------------------------------------------
// final_gemm: out[n,o] = sum_e s[n,e]*(bias[e,o] + sum_ki XG[n,ki]*W[e,ki,o])
// (unchanged from round 2)
// ---------------------------------------------------------------------------
__global__ __launch_bounds__(256, 1) void final_gemm(
    const float* __restrict__ x,
    const float* __restrict__ y1,
    const float* __restrict__ y2,
    const float* __restrict__ stock,
    const float* __restrict__ wt,
    const float* __restrict__ bias,
    float* __restrict__ out)
{
    __shared__ alignas(16) float w_s[24 * 32 * 20];
    __shared__ alignas(16) float xg_t[96 * 68];
    __shared__ alignas(16) float s_s[64 * 16];

    const int tid  = threadIdx.x;
    const int o    = tid & 31;
    const int rg   = tid >> 5;
    const int row0 = blockIdx.x << 6;
    const int sw   = (o + (o >> 3)) & 3;

    #pragma unroll
    for (int qv = 0; qv < 2; ++qv) {
        int f = qv * 256 + tid;
        int r = f >> 3, i4 = (f & 7) << 2;
        size_t g = (size_t)(row0 + r) * 32 + i4;
        float4 xv  = *(const float4*)(x + g);
        float4 y1v = *(const float4*)(y1 + g);
        float4 y2v = *(const float4*)(y2 + g);
        #pragma unroll
        for (int jj = 0; jj < 4; ++jj) {
            float xs  = ((const float*)&xv)[jj];
            float y1s = ((const float*)&y1v)[jj];
            float y2s = ((const float*)&y2v)[jj];
            int i = i4 + jj;
            xg_t[i * 68 + r]        = xs;
            xg_t[(32 + i) * 68 + r] = y1s;
            xg_t[(64 + i) * 68 + r] = 2.f * y2s - xs;
        }
    }
    {
        int r = tid >> 2, e4 = (tid & 3) << 2;
        *(float4*)(&s_s[r * 16 + e4]) = *(const float4*)(stock + (size_t)(row0 + r) * 16 + e4);
    }

    float bv[16];
    #pragma unroll
    for (int e = 0; e < 16; ++e) bv[e] = bias[e * 32 + o];

    float acc[8][16];
    #pragma unroll
    for (int r = 0; r < 8; ++r)
        #pragma unroll
        for (int e = 0; e < 16; ++e) acc[r][e] = 0.f;

    for (int ch = 0; ch < 4; ++ch) {
        __syncthreads();
        const float4* src = (const float4*)(wt + ch * 15360);
        float4* dst = (float4*)w_s;
        #pragma unroll
        for (int qv = 0; qv < 15; ++qv)
            dst[qv * 256 + tid] = src[qv * 256 + tid];
        __syncthreads();

        for (int kl = 0; kl < 24; ++kl) {
            const int kg = ch * 24 + kl;
            float xr[8];
            *(float4*)&xr[0] = *(const float4*)(xg_t + kg * 68 + rg * 8);
            *(float4*)&xr[4] = *(const float4*)(xg_t + kg * 68 + rg * 8 + 4);
            const float* wb = w_s + (kl * 32 + o) * 20;
            float we[16];
            #pragma unroll
            for (int j = 0; j < 4; ++j)
                *(float4*)&we[4 * j] = *(const float4*)(wb + ((j ^ sw) << 2));
            #pragma unroll
            for (int e = 0; e < 16; ++e)
                #pragma unroll
                for (int r = 0; r < 8; ++r)
                    acc[r][e] = fmaf(xr[r], we[e], acc[r][e]);
        }
    }

    #pragma unroll
    for (int r = 0; r < 8; ++r) {
        const int row = rg * 8 + r;
        float sum = 0.f;
        #pragma unroll
        for (int e = 0; e < 16; ++e)
            sum = fmaf(s_s[row * 16 + e], acc[r][e] + bv[e], sum);
        out[(size_t)(row0 + row) * 32 + o] = sum;
    }
}

extern "C" void kernel_launch(void* const* d_in, const int* in_sizes, int n_in,
                              void* d_out, int out_size, void* d_ws, size_t ws_size,
                              hipStream_t stream) {
    const float* x     = (const float*)d_in[0];
    const float* aemb  = (const float*)d_in[1];
    const float* stock = (const float*)d_in[2];
    const float* Wp    = (const float*)d_in[3];
    const float* bias  = (const float*)d_in[4];
    float* out = (float*)d_out;

    float*  ws  = (float*)d_ws;
    float*  y1  = ws;                       // 524288 floats
    float*  y2  = ws + 524288;              // 524288 floats
    float*  wtb = ws + 1048576;             // 61440 floats
    __bf16* es  = (__bf16*)(ws + 1110016);  // 524288 bf16
    __bf16* vt  = (__bf16*)(ws + 1372160);  // 1048576 bf16

    k_es       <<<dim3(256), dim3(256), 0, stream>>>(aemb, es);
    k_tr       <<<dim3(256), dim3(256), 0, stream>>>(x, vt);
    w_transpose<<<dim3(240), dim3(256), 0, stream>>>(Wp, wtb);
    apply_mfma <<<dim3(512), dim3(256), 0, stream>>>(es, vt, y1);
    k_tr       <<<dim3(256), dim3(256), 0, stream>>>(y1, vt);
    apply_mfma <<<dim3(512), dim3(256), 0, stream>>>(es, vt, y2);
    final_gemm <<<dim3(256), dim3(256), 0, stream>>>(x, y1, y2, stock, wtb, bias, out);
}

// Round 5
// 42.058 us; speedup vs baseline: 3.1375x; 1.5422x over previous
//
#include <hip/hip_runtime.h>
#include <stdint.h>

typedef __bf16 bf16x8 __attribute__((ext_vector_type(8)));
typedef __bf16 bf16x4 __attribute__((ext_vector_type(4)));
typedef float  f32x16 __attribute__((ext_vector_type(16)));

constexpr int kB = 16;
constexpr int kN = 1024;
constexpr int kE = 16;

struct bfhl { __bf16 h, l; };
__device__ __forceinline__ bfhl hilo(float v) {
    bfhl r;
    r.h = (__bf16)v;
    r.l = (__bf16)(v - (float)r.h);
    return r;
}

// ---------------------------------------------------------------------------
// prep (fused): blocks 0..255  : k_es   — emb fp32 -> es [n][32] bf16 (hi|lo)
//               blocks 256..511: k_tr_x — x -> vt1 [b][pl][32][1024] bf16 AND
//                                         xgb slice k=0..31 ([n][pl][96])
//               blocks 512..535: w_prep — Wp fp32 -> wq [e][pl][ks][o][h][8]
// ---------------------------------------------------------------------------
__global__ __launch_bounds__(256) void prep(
    const float* __restrict__ emb, const float* __restrict__ x,
    const float* __restrict__ Wp,
    __bf16* __restrict__ es, __bf16* __restrict__ vt1,
    __bf16* __restrict__ xgb, __bf16* __restrict__ wq)
{
    __shared__ float ls[64 * 33];
    const int tid = threadIdx.x;
    const int bid = blockIdx.x;

    if (bid < 256) {
        int c = bid * 256 + tid;            // 16B chunk id
        int row = c >> 2, seg = c & 3;
        float4 v = *(const float4*)(emb + (size_t)c * 4);
        float f[4] = {v.x, v.y, v.z, v.w};
        bf16x4 hi, lo;
        #pragma unroll
        for (int i = 0; i < 4; ++i) { bfhl t = hilo(f[i]); hi[i] = t.h; lo[i] = t.l; }
        __bf16* r = es + (size_t)row * 32;
        *(bf16x4*)(r + seg * 4)      = hi;
        *(bf16x4*)(r + 16 + seg * 4) = lo;
    } else if (bid < 512) {
        const int bb = bid - 256;
        const int b = bb >> 4, n0 = (bb & 15) << 6;
        const float* sB = x + ((size_t)b * kN + n0) * 32;
        #pragma unroll
        for (int it = 0; it < 2; ++it) {
            int f = it * 256 + tid;
            int row = f >> 3, q8 = f & 7;
            float4 v = *(const float4*)(sB + (size_t)row * 32 + q8 * 4);
            ls[row * 33 + q8 * 4 + 0] = v.x;
            ls[row * 33 + q8 * 4 + 1] = v.y;
            ls[row * 33 + q8 * 4 + 2] = v.z;
            ls[row * 33 + q8 * 4 + 3] = v.w;
        }
        __syncthreads();
        {   // vt1: transposed hi/lo
            const int p = tid >> 7, d = (tid >> 2) & 31, ng = tid & 3;
            bf16x8 o0, o1;
            #pragma unroll
            for (int i = 0; i < 16; ++i) {
                float v = ls[(ng * 16 + i) * 33 + d];
                __bf16 h = (__bf16)v;
                __bf16 o = (p == 0) ? h : (__bf16)(v - (float)h);
                if (i < 8) o0[i] = o; else o1[i - 8] = o;
            }
            __bf16* dp = vt1 + (size_t)b * 65536 + (size_t)p * 32768 + (size_t)d * 1024 + n0 + ng * 16;
            *(bf16x8*)dp       = o0;
            *(bf16x8*)(dp + 8) = o1;
        }
        {   // xgb slice 0..31
            const int r2 = tid >> 2, jg = tid & 3;
            bf16x8 hi, lo;
            #pragma unroll
            for (int i = 0; i < 8; ++i) {
                bfhl t = hilo(ls[r2 * 33 + jg * 8 + i]);
                hi[i] = t.h; lo[i] = t.l;
            }
            __bf16* dp = xgb + (size_t)(b * kN + n0 + r2) * 192 + jg * 8;
            *(bf16x8*)dp        = hi;
            *(bf16x8*)(dp + 96) = lo;
        }
    } else {
        int idx = (bid - 512) * 256 + tid;   // (e, ks, o, h)
        if (idx < 6144) {
            int e = idx / 384, rem = idx - e * 384;
            int ks = rem / 64, r2 = rem - ks * 64;
            int o = r2 >> 1, h = r2 & 1;
            int ki0 = ks * 16 + h * 8;
            bf16x8 hi, lo;
            #pragma unroll
            for (int j = 0; j < 8; ++j) {
                bfhl t = hilo(Wp[(size_t)e * 3072 + (size_t)(ki0 + j) * 32 + o]);
                hi[j] = t.h; lo[j] = t.l;
            }
            *(bf16x8*)(wq + (size_t)((e * 2 + 0) * 6 + ks) * 512 + o * 16 + h * 8) = hi;
            *(bf16x8*)(wq + (size_t)((e * 2 + 1) * 6 + ks) * 512 + o * 16 + h * 8) = lo;
        }
    }
}

// ---------------------------------------------------------------------------
// apply_mfma<STAGE>: Y = softmax_row(relu(E E^T)) @ V via bf16 MFMA 32x32x16.
// STAGE 1: V = vt1(x);  writes vt2 (for stage 2) + xgb slice k=32..63 (y1)
// STAGE 2: V = vt2(y1); writes xgb slice k=64..95 (2*y2 - x)
// grid 512, 256 threads (4 waves, kk-split). Core identical to round 3.
// ---------------------------------------------------------------------------
template<int STAGE>
__global__ __launch_bounds__(256, 2) void apply_mfma(
    const __bf16* __restrict__ es,    // [B][1024][32]
    const __bf16* __restrict__ vtin,  // [B][2][32][1024]
    const float*  __restrict__ x,     // [B,N,32] (STAGE 2 only)
    __bf16* __restrict__ vt2,         // STAGE 1 out
    __bf16* __restrict__ xgb)         // [n][2][96]
{
    __shared__ __bf16 es_s[256 * 36];
    __shared__ __bf16 vt_s[2 * 32 * 260];
    __shared__ float  ps[4 * 32 * 33];
    __shared__ float  Ls[4 * 32];
    __shared__ float  yb[32 * 33];

    const int tid = threadIdx.x;
    const int w = tid >> 6, l = tid & 63;
    const int q = l & 31, h = l >> 5;
    const int b = blockIdx.x >> 5, q0 = (blockIdx.x & 31) << 5;

    const __bf16* esB = es + (size_t)b * 32768;
    const __bf16* vtB = vtin + (size_t)b * 65536;

    const __bf16* qr = esB + (size_t)(q0 + q) * 32;
    bf16x8 bhi = *(const bf16x8*)(qr + 8 * h);
    bf16x8 blo = *(const bf16x8*)(qr + 16 + 8 * h);

    f32x16 acc = {};
    float Lp = 0.f;

    for (int ch = 0; ch < 4; ++ch) {
        __syncthreads();
        #pragma unroll
        for (int i = 0; i < 4; ++i) {
            int f = i * 256 + tid;
            int rl = f >> 2, seg = f & 3;
            bf16x8 v = *(const bf16x8*)(esB + (size_t)(ch * 256 + rl) * 32 + seg * 8);
            bf16x4 v0, v1;
            #pragma unroll
            for (int j = 0; j < 4; ++j) { v0[j] = v[j]; v1[j] = v[4 + j]; }
            *(bf16x4*)(es_s + rl * 36 + seg * 8)     = v0;
            *(bf16x4*)(es_s + rl * 36 + seg * 8 + 4) = v1;
        }
        #pragma unroll
        for (int i = 0; i < 8; ++i) {
            int f = i * 256 + tid;
            int r = f >> 5, c16 = f & 31;
            bf16x8 v = *(const bf16x8*)(vtB + (size_t)r * 1024 + ch * 256 + c16 * 8);
            bf16x4 v0, v1;
            #pragma unroll
            for (int j = 0; j < 4; ++j) { v0[j] = v[j]; v1[j] = v[4 + j]; }
            *(bf16x4*)(vt_s + r * 260 + c16 * 8)     = v0;
            *(bf16x4*)(vt_s + r * 260 + c16 * 8 + 4) = v1;
        }
        __syncthreads();

        #pragma unroll
        for (int sub = 0; sub < 2; ++sub) {
            const int kbl = (w << 6) + (sub << 5);
            const __bf16* ar = es_s + (size_t)(kbl + q) * 36;
            bf16x4 a0 = *(const bf16x4*)(ar + 8 * h);
            bf16x4 a1 = *(const bf16x4*)(ar + 8 * h + 4);
            bf16x4 a2 = *(const bf16x4*)(ar + 16 + 8 * h);
            bf16x4 a3 = *(const bf16x4*)(ar + 16 + 8 * h + 4);
            bf16x8 ahi, alo;
            #pragma unroll
            for (int j = 0; j < 4; ++j) {
                ahi[j] = a0[j]; ahi[4 + j] = a1[j];
                alo[j] = a2[j]; alo[4 + j] = a3[j];
            }
            f32x16 S = {};
            S = __builtin_amdgcn_mfma_f32_32x32x16_bf16(ahi, bhi, S, 0, 0, 0);
            S = __builtin_amdgcn_mfma_f32_32x32x16_bf16(ahi, blo, S, 0, 0, 0);
            S = __builtin_amdgcn_mfma_f32_32x32x16_bf16(alo, bhi, S, 0, 0, 0);
            S = __builtin_amdgcn_mfma_f32_32x32x16_bf16(alo, blo, S, 0, 0, 0);

            float p[16];
            #pragma unroll
            for (int r = 0; r < 16; ++r) {
                p[r] = __expf(fmaxf(S[r], 0.f));
                Lp += p[r];
            }
            bf16x8 P0, P1;
            #pragma unroll
            for (int j = 0; j < 8; ++j) { P0[j] = (__bf16)p[j]; P1[j] = (__bf16)p[8 + j]; }

            const __bf16* vh = vt_s + (size_t)q * 260;
            const __bf16* vl = vt_s + 32 * 260 + (size_t)q * 260;
            bf16x4 w0a = *(const bf16x4*)(vh + kbl + 4 * h);
            bf16x4 w0b = *(const bf16x4*)(vh + kbl + 8 + 4 * h);
            bf16x4 w1a = *(const bf16x4*)(vh + kbl + 16 + 4 * h);
            bf16x4 w1b = *(const bf16x4*)(vh + kbl + 24 + 4 * h);
            bf16x4 w0c = *(const bf16x4*)(vl + kbl + 4 * h);
            bf16x4 w0d = *(const bf16x4*)(vl + kbl + 8 + 4 * h);
            bf16x4 w1c = *(const bf16x4*)(vl + kbl + 16 + 4 * h);
            bf16x4 w1d = *(const bf16x4*)(vl + kbl + 24 + 4 * h);
            bf16x8 A0h, A0l, A1h, A1l;
            #pragma unroll
            for (int j = 0; j < 4; ++j) {
                A0h[j] = w0a[j]; A0h[4 + j] = w0b[j];
                A0l[j] = w0c[j]; A0l[4 + j] = w0d[j];
                A1h[j] = w1a[j]; A1h[4 + j] = w1b[j];
                A1l[j] = w1c[j]; A1l[4 + j] = w1d[j];
            }
            acc = __builtin_amdgcn_mfma_f32_32x32x16_bf16(A0h, P0, acc, 0, 0, 0);
            acc = __builtin_amdgcn_mfma_f32_32x32x16_bf16(A0l, P0, acc, 0, 0, 0);
            acc = __builtin_amdgcn_mfma_f32_32x32x16_bf16(A1h, P1, acc, 0, 0, 0);
            acc = __builtin_amdgcn_mfma_f32_32x32x16_bf16(A1l, P1, acc, 0, 0, 0);
        }
    }

    Lp += __shfl_xor(Lp, 32);
    #pragma unroll
    for (int r = 0; r < 16; ++r) {
        int d = (r & 3) + 8 * (r >> 2) + 4 * h;
        ps[w * 1056 + d * 33 + q] = acc[r];
    }
    if (l < 32) Ls[w * 32 + l] = Lp;
    __syncthreads();

    // merged y for this thread: node qq, dims dg*4..+3
    const int qq = tid >> 3, dg = tid & 7;
    const float iL = 1.f / (Ls[qq] + Ls[32 + qq] + Ls[64 + qq] + Ls[96 + qq]);
    float yv[4];
    #pragma unroll
    for (int i = 0; i < 4; ++i) {
        int d = dg * 4 + i;
        yv[i] = (ps[d * 33 + qq] + ps[1056 + d * 33 + qq] +
                 ps[2112 + d * 33 + qq] + ps[3168 + d * 33 + qq]) * iL;
    }

    // xgb slice write (k = 32..63 for STAGE 1, 64..95 with 2*y2-x for STAGE 2)
    {
        float src[4];
        if (STAGE == 2) {
            float4 xv = *(const float4*)(x + (size_t)(b * kN + q0 + qq) * 32 + dg * 4);
            src[0] = 2.f * yv[0] - xv.x; src[1] = 2.f * yv[1] - xv.y;
            src[2] = 2.f * yv[2] - xv.z; src[3] = 2.f * yv[3] - xv.w;
        } else {
            #pragma unroll
            for (int i = 0; i < 4; ++i) src[i] = yv[i];
        }
        const int koff = (STAGE == 1) ? 32 : 64;
        bf16x4 hi, lo;
        #pragma unroll
        for (int i = 0; i < 4; ++i) { bfhl t = hilo(src[i]); hi[i] = t.h; lo[i] = t.l; }
        __bf16* dp = xgb + (size_t)(b * kN + q0 + qq) * 192 + koff + dg * 4;
        *(bf16x4*)dp        = hi;
        *(bf16x4*)(dp + 96) = lo;
    }

    if (STAGE == 1) {
        #pragma unroll
        for (int i = 0; i < 4; ++i) yb[qq * 33 + dg * 4 + i] = yv[i];
        __syncthreads();
        const int d = tid >> 3, qg = tid & 7;
        bf16x4 hi, lo;
        #pragma unroll
        for (int i = 0; i < 4; ++i) {
            bfhl t = hilo(yb[(qg * 4 + i) * 33 + d]);
            hi[i] = t.h; lo[i] = t.l;
        }
        __bf16* dp = vt2 + (size_t)b * 65536 + (size_t)d * 1024 + q0 + qg * 4;
        *(bf16x4*)dp          = hi;
        *(bf16x4*)(dp + 32768) = lo;
    }
}

// ---------------------------------------------------------------------------
// final_mfma: out[n,o] = sum_e s[n,e]*(bias[e,o] + sum_ki XG[n,ki] W[e,ki,o])
// grid 512 (32 nodes/block), 4 waves; wave w owns e = 4w..4w+3 (one 32x32
// MFMA tile per e: rows=nodes, cols=o). A (XG) from LDS; B (W) streamed
// from L2 in fragment-contiguous layout (1KB coalesced per load).
// bf16 hi/lo 3-term product; fp32 epilogue contraction over e + bias.
// ---------------------------------------------------------------------------
__global__ __launch_bounds__(256, 2) void final_mfma(
    const __bf16* __restrict__ xgb,   // [16384][2][96]
    const float*  __restrict__ stock, // [16384][16]
    const __bf16* __restrict__ wq,    // [e][pl][ks][o][h][8]
    const float*  __restrict__ bias,  // [16][32]
    float* __restrict__ out)          // [16384][32]
{
    __shared__ __bf16 xga[2 * 32 * 104];   // [pl][node][104] (4-way max)
    __shared__ float  s_s[32 * 16];
    __shared__ float  ps[4 * 32 * 33];

    const int tid = threadIdx.x;
    const int w = tid >> 6, l = tid & 63;
    const int o = l & 31, h = l >> 5;
    const int n0 = blockIdx.x << 5;

    #pragma unroll
    for (int it = 0; it < 3; ++it) {
        int c = it * 256 + tid;            // 768 chunks of 16B
        int n = c / 24, r = c - n * 24;
        int pl = r / 12, s12 = r - pl * 12;
        bf16x8 v = *(const bf16x8*)(xgb + (size_t)(n0 + n) * 192 + pl * 96 + s12 * 8);
        *(bf16x8*)(xga + pl * 3328 + n * 104 + s12 * 8) = v;
    }
    {
        int r = tid >> 3, e2 = (tid & 7) * 2;
        *(float2*)(s_s + r * 16 + e2) = *(const float2*)(stock + (size_t)(n0 + r) * 16 + e2);
    }
    __syncthreads();

    f32x16 acc[4] = {};
    const int e0 = w * 4;

    #pragma unroll
    for (int ks = 0; ks < 6; ++ks) {
        bf16x8 Ah = *(const bf16x8*)(xga + o * 104 + ks * 16 + 8 * h);
        bf16x8 Al = *(const bf16x8*)(xga + 3328 + o * 104 + ks * 16 + 8 * h);
        #pragma unroll
        for (int ei = 0; ei < 4; ++ei) {
            const __bf16* wb = wq + (size_t)(((e0 + ei) * 2 + 0) * 6 + ks) * 512 + o * 16 + h * 8;
            const __bf16* wl = wq + (size_t)(((e0 + ei) * 2 + 1) * 6 + ks) * 512 + o * 16 + h * 8;
            bf16x8 Bh = *(const bf16x8*)wb;
            bf16x8 Bl = *(const bf16x8*)wl;
            acc[ei] = __builtin_amdgcn_mfma_f32_32x32x16_bf16(Ah, Bh, acc[ei], 0, 0, 0);
            acc[ei] = __builtin_amdgcn_mfma_f32_32x32x16_bf16(Ah, Bl, acc[ei], 0, 0, 0);
            acc[ei] = __builtin_amdgcn_mfma_f32_32x32x16_bf16(Al, Bh, acc[ei], 0, 0, 0);
        }
    }

    float pr[16];
    #pragma unroll
    for (int r = 0; r < 16; ++r) pr[r] = 0.f;
    #pragma unroll
    for (int ei = 0; ei < 4; ++ei) {
        const int eg = e0 + ei;
        const float bv = bias[eg * 32 + o];
        #pragma unroll
        for (int r = 0; r < 16; ++r) {
            int node = (r & 3) + 8 * (r >> 2) + 4 * h;
            pr[r] += s_s[node * 16 + eg] * (acc[ei][r] + bv);
        }
    }
    #pragma unroll
    for (int r = 0; r < 16; ++r) {
        int node = (r & 3) + 8 * (r >> 2) + 4 * h;
        ps[w * 1056 + node * 33 + o] = pr[r];
    }
    __syncthreads();
    {
        const int node = tid >> 3, og = (tid & 7) * 4;
        float4 s;
        #pragma unroll
        for (int i = 0; i < 4; ++i) {
            int c = node * 33 + og + i;
            ((float*)&s)[i] = ps[c] + ps[1056 + c] + ps[2112 + c] + ps[3168 + c];
        }
        *(float4*)(out + (size_t)(n0 + node) * 32 + og) = s;
    }
}

extern "C" void kernel_launch(void* const* d_in, const int* in_sizes, int n_in,
                              void* d_out, int out_size, void* d_ws, size_t ws_size,
                              hipStream_t stream) {
    const float* x     = (const float*)d_in[0];
    const float* aemb  = (const float*)d_in[1];
    const float* stock = (const float*)d_in[2];
    const float* Wp    = (const float*)d_in[3];
    const float* bias  = (const float*)d_in[4];
    float* out = (float*)d_out;

    float*  ws  = (float*)d_ws;
    __bf16* es  = (__bf16*)ws;                  // 524288 bf16
    __bf16* vt1 = (__bf16*)(ws + 262144);       // 1048576 bf16
    __bf16* vt2 = (__bf16*)(ws + 786432);       // 1048576 bf16
    __bf16* xgb = (__bf16*)(ws + 1310720);      // 3145728 bf16
    __bf16* wq  = (__bf16*)(ws + 2883584);      // 98304 bf16

    prep<<<dim3(536), dim3(256), 0, stream>>>(aemb, x, Wp, es, vt1, xgb, wq);
    apply_mfma<1><<<dim3(512), dim3(256), 0, stream>>>(es, vt1, x, vt2, xgb);
    apply_mfma<2><<<dim3(512), dim3(256), 0, stream>>>(es, vt2, x, vt2, xgb);
    final_mfma<<<dim3(512), dim3(256), 0, stream>>>(xgb, stock, wq, bias, out);
}

// Round 6
// 33.369 us; speedup vs baseline: 3.9545x; 1.2604x over previous
//
#include <hip/hip_runtime.h>
#include <stdint.h>

typedef __bf16 bf16x8 __attribute__((ext_vector_type(8)));
typedef __bf16 bf16x4 __attribute__((ext_vector_type(4)));
typedef float  f32x16 __attribute__((ext_vector_type(16)));

constexpr int kB = 16;
constexpr int kN = 1024;
constexpr int kE = 16;

struct bfhl { __bf16 h, l; };
__device__ __forceinline__ bfhl hilo(float v) {
    bfhl r;
    r.h = (__bf16)v;
    r.l = (__bf16)(v - (float)r.h);
    return r;
}

// ---------------------------------------------------------------------------
// prep (fused): blocks 0..255  : emb fp32 -> es [n][32] bf16 (16 hi | 16 lo)
//               blocks 256..511: x -> vt1 hi-plane [b][32][1024] bf16 AND
//                                xgb slice k=0..31 ([n][2][96])
//               blocks 512..535: Wp fp32 -> wq [e][ks][o][h][8] (hi only)
// ---------------------------------------------------------------------------
__global__ __launch_bounds__(256) void prep(
    const float* __restrict__ emb, const float* __restrict__ x,
    const float* __restrict__ Wp,
    __bf16* __restrict__ es, __bf16* __restrict__ vt1,
    __bf16* __restrict__ xgb, __bf16* __restrict__ wq)
{
    __shared__ float ls[64 * 33];
    const int tid = threadIdx.x;
    const int bid = blockIdx.x;

    if (bid < 256) {
        int c = bid * 256 + tid;            // 16B chunk id
        int row = c >> 2, seg = c & 3;
        float4 v = *(const float4*)(emb + (size_t)c * 4);
        float f[4] = {v.x, v.y, v.z, v.w};
        bf16x4 hi, lo;
        #pragma unroll
        for (int i = 0; i < 4; ++i) { bfhl t = hilo(f[i]); hi[i] = t.h; lo[i] = t.l; }
        __bf16* r = es + (size_t)row * 32;
        *(bf16x4*)(r + seg * 4)      = hi;
        *(bf16x4*)(r + 16 + seg * 4) = lo;
    } else if (bid < 512) {
        const int bb = bid - 256;
        const int b = bb >> 4, n0 = (bb & 15) << 6;
        const float* sB = x + ((size_t)b * kN + n0) * 32;
        #pragma unroll
        for (int it = 0; it < 2; ++it) {
            int f = it * 256 + tid;
            int row = f >> 3, q8 = f & 7;
            float4 v = *(const float4*)(sB + (size_t)row * 32 + q8 * 4);
            ls[row * 33 + q8 * 4 + 0] = v.x;
            ls[row * 33 + q8 * 4 + 1] = v.y;
            ls[row * 33 + q8 * 4 + 2] = v.z;
            ls[row * 33 + q8 * 4 + 3] = v.w;
        }
        __syncthreads();
        if (tid < 128) {   // vt1 hi-plane: transposed
            const int d = (tid >> 2) & 31, ng = tid & 3;
            bf16x8 o0, o1;
            #pragma unroll
            for (int i = 0; i < 16; ++i) {
                __bf16 hcast = (__bf16)ls[(ng * 16 + i) * 33 + d];
                if (i < 8) o0[i] = hcast; else o1[i - 8] = hcast;
            }
            __bf16* dp = vt1 + (size_t)b * 65536 + (size_t)d * 1024 + n0 + ng * 16;
            *(bf16x8*)dp       = o0;
            *(bf16x8*)(dp + 8) = o1;
        }
        {   // xgb slice 0..31
            const int r2 = tid >> 2, jg = tid & 3;
            bf16x8 hi, lo;
            #pragma unroll
            for (int i = 0; i < 8; ++i) {
                bfhl t = hilo(ls[r2 * 33 + jg * 8 + i]);
                hi[i] = t.h; lo[i] = t.l;
            }
            __bf16* dp = xgb + (size_t)(b * kN + n0 + r2) * 192 + jg * 8;
            *(bf16x8*)dp        = hi;
            *(bf16x8*)(dp + 96) = lo;
        }
    } else {
        int idx = (bid - 512) * 256 + tid;   // (e, ks, o, h)
        if (idx < 6144) {
            int e = idx / 384, rem = idx - e * 384;
            int ks = rem / 64, r2 = rem - ks * 64;
            int o = r2 >> 1, h = r2 & 1;
            int ki0 = ks * 16 + h * 8;
            bf16x8 hi;
            #pragma unroll
            for (int j = 0; j < 8; ++j)
                hi[j] = (__bf16)Wp[(size_t)e * 3072 + (size_t)(ki0 + j) * 32 + o];
            *(bf16x8*)(wq + (size_t)(e * 6 + ks) * 512 + o * 16 + h * 8) = hi;
        }
    }
}

// ---------------------------------------------------------------------------
// apply_mfma<STAGE>: Y = softmax_row(relu(E E^T)) @ V via bf16 MFMA 32x32x16.
// STAGE 1: V = vt1(x);  writes vt2 (hi) + xgb slice k=32..63 (y1)
// STAGE 2: V = vt2(y1); writes xgb slice k=64..95 (2*y2 - x)
// All LDS traffic 16B-granular, conflict-optimal layouts:
//   es_s rows 80B (16B aligned); vt_s rows 528B, content m~-permuted
//   (bit2<->3 swap within 16-groups) so PV A-fragments are contiguous b128.
// QK 3-term hi/lo (ll dropped ~2^-18); PV hi-plane only (~2^-9 |V|).
// ---------------------------------------------------------------------------
template<int STAGE>
__global__ __launch_bounds__(256, 2) void apply_mfma(
    const __bf16* __restrict__ es,    // [B][1024][32]
    const __bf16* __restrict__ vtin,  // [B][2][32][1024] (hi plane used)
    const float*  __restrict__ x,     // STAGE 2 only
    __bf16* __restrict__ vt2,
    __bf16* __restrict__ xgb)         // [n][2][96]
{
    __shared__ __bf16 es_s[256 * 40];   // 20.0 KB
    __shared__ __bf16 vt_s[32 * 264];   // 16.5 KB
    __shared__ float  ps[4 * 32 * 33];  // 16.9 KB
    __shared__ float  Ls[4 * 32];
    __shared__ float  yb[32 * 33];

    const int tid = threadIdx.x;
    const int w = tid >> 6, l = tid & 63;
    const int q = l & 31, h = l >> 5;
    const int b = blockIdx.x >> 5, q0 = (blockIdx.x & 31) << 5;

    const __bf16* esB = es + (size_t)b * 32768;
    const __bf16* vtB = vtin + (size_t)b * 65536;   // hi plane

    const __bf16* qr = esB + (size_t)(q0 + q) * 32;
    bf16x8 bhi = *(const bf16x8*)(qr + 8 * h);
    bf16x8 blo = *(const bf16x8*)(qr + 16 + 8 * h);

    f32x16 acc = {};
    float Lp = 0.f;

    for (int ch = 0; ch < 4; ++ch) {
        __syncthreads();
        // stage es chunk: 256 rows x 64B, direct 16B copies
        #pragma unroll
        for (int i = 0; i < 4; ++i) {
            int f = i * 256 + tid;
            int rl = f >> 2, c = f & 3;
            bf16x8 v = *(const bf16x8*)(esB + (size_t)(ch * 256 + rl) * 32 + c * 8);
            *(bf16x8*)(es_s + rl * 40 + c * 8) = v;
        }
        // stage vt chunk (hi plane): 32 d x 256 m, m~-permute per 16-group
        #pragma unroll
        for (int it = 0; it < 2; ++it) {
            int G = it * 256 + tid;
            int d = G >> 4, g = G & 15;
            const __bf16* src = vtB + (size_t)d * 1024 + ch * 256 + g * 16;
            bf16x8 in0 = *(const bf16x8*)src;
            bf16x8 in1 = *(const bf16x8*)(src + 8);
            bf16x8 out0 = __builtin_shufflevector(in0, in1, 0, 1, 2, 3, 8, 9, 10, 11);
            bf16x8 out1 = __builtin_shufflevector(in0, in1, 4, 5, 6, 7, 12, 13, 14, 15);
            *(bf16x8*)(vt_s + d * 264 + g * 16)     = out0;
            *(bf16x8*)(vt_s + d * 264 + g * 16 + 8) = out1;
        }
        __syncthreads();

        #pragma unroll
        for (int sub = 0; sub < 2; ++sub) {
            const int kbl = (w << 6) + (sub << 5);
            const __bf16* ar = es_s + (size_t)(kbl + q) * 40;
            bf16x8 ahi = *(const bf16x8*)(ar + 8 * h);
            bf16x8 alo = *(const bf16x8*)(ar + 16 + 8 * h);

            f32x16 S = {};
            S = __builtin_amdgcn_mfma_f32_32x32x16_bf16(ahi, bhi, S, 0, 0, 0);
            S = __builtin_amdgcn_mfma_f32_32x32x16_bf16(ahi, blo, S, 0, 0, 0);
            S = __builtin_amdgcn_mfma_f32_32x32x16_bf16(alo, bhi, S, 0, 0, 0);

            float p[16];
            #pragma unroll
            for (int r = 0; r < 16; ++r) {
                p[r] = __expf(fmaxf(S[r], 0.f));
                Lp += p[r];
            }
            bf16x8 P0, P1;
            #pragma unroll
            for (int j = 0; j < 8; ++j) { P0[j] = (__bf16)p[j]; P1[j] = (__bf16)p[8 + j]; }

            const __bf16* vh = vt_s + (size_t)q * 264 + kbl;   // lane index = d
            bf16x8 A0 = *(const bf16x8*)(vh + 8 * h);
            bf16x8 A1 = *(const bf16x8*)(vh + 16 + 8 * h);
            acc = __builtin_amdgcn_mfma_f32_32x32x16_bf16(A0, P0, acc, 0, 0, 0);
            acc = __builtin_amdgcn_mfma_f32_32x32x16_bf16(A1, P1, acc, 0, 0, 0);
        }
    }

    Lp += __shfl_xor(Lp, 32);
    #pragma unroll
    for (int r = 0; r < 16; ++r) {
        int d = (r & 3) + 8 * (r >> 2) + 4 * h;
        ps[w * 1056 + d * 33 + q] = acc[r];
    }
    if (l < 32) Ls[w * 32 + l] = Lp;
    __syncthreads();

    // merged y for this thread: node qq, dims dg*4..+3
    const int qq = tid >> 3, dg = tid & 7;
    const float iL = 1.f / (Ls[qq] + Ls[32 + qq] + Ls[64 + qq] + Ls[96 + qq]);
    float yv[4];
    #pragma unroll
    for (int i = 0; i < 4; ++i) {
        int d = dg * 4 + i;
        yv[i] = (ps[d * 33 + qq] + ps[1056 + d * 33 + qq] +
                 ps[2112 + d * 33 + qq] + ps[3168 + d * 33 + qq]) * iL;
    }

    // xgb slice write (k = 32..63 for STAGE 1, 64..95 with 2*y2-x for STAGE 2)
    {
        float src[4];
        if (STAGE == 2) {
            float4 xv = *(const float4*)(x + (size_t)(b * kN + q0 + qq) * 32 + dg * 4);
            src[0] = 2.f * yv[0] - xv.x; src[1] = 2.f * yv[1] - xv.y;
            src[2] = 2.f * yv[2] - xv.z; src[3] = 2.f * yv[3] - xv.w;
        } else {
            #pragma unroll
            for (int i = 0; i < 4; ++i) src[i] = yv[i];
        }
        const int koff = (STAGE == 1) ? 32 : 64;
        bf16x4 hi, lo;
        #pragma unroll
        for (int i = 0; i < 4; ++i) { bfhl t = hilo(src[i]); hi[i] = t.h; lo[i] = t.l; }
        __bf16* dp = xgb + (size_t)(b * kN + q0 + qq) * 192 + koff + dg * 4;
        *(bf16x4*)dp        = hi;
        *(bf16x4*)(dp + 96) = lo;
    }

    if (STAGE == 1) {
        #pragma unroll
        for (int i = 0; i < 4; ++i) yb[qq * 33 + dg * 4 + i] = yv[i];
        __syncthreads();
        const int d = tid >> 3, qg = tid & 7;
        bf16x4 hi;
        #pragma unroll
        for (int i = 0; i < 4; ++i) hi[i] = (__bf16)yb[(qg * 4 + i) * 33 + d];
        *(bf16x4*)(vt2 + (size_t)b * 65536 + (size_t)d * 1024 + q0 + qg * 4) = hi;
    }
}

// ---------------------------------------------------------------------------
// final_mfma: out[n,o] = sum_e s[n,e]*(bias[e,o] + sum_ki XG[n,ki] W[e,ki,o])
// grid 512 (32 nodes/block), wave w owns e = 4w..4w+3. A (XG, 2-plane) from
// LDS; B (W, hi only) streamed from L2 fragment-contiguous (1KB/wave-load).
// ---------------------------------------------------------------------------
__global__ __launch_bounds__(256, 2) void final_mfma(
    const __bf16* __restrict__ xgb,   // [16384][2][96]
    const float*  __restrict__ stock, // [16384][16]
    const __bf16* __restrict__ wq,    // [e][ks][o][h][8] hi plane
    const float*  __restrict__ bias,  // [16][32]
    float* __restrict__ out)          // [16384][32]
{
    __shared__ __bf16 xga[2 * 32 * 104];
    __shared__ float  s_s[32 * 16];
    __shared__ float  ps[4 * 32 * 33];

    const int tid = threadIdx.x;
    const int w = tid >> 6, l = tid & 63;
    const int o = l & 31, h = l >> 5;
    const int n0 = blockIdx.x << 5;

    #pragma unroll
    for (int it = 0; it < 3; ++it) {
        int c = it * 256 + tid;            // 768 chunks of 16B
        int n = c / 24, r = c - n * 24;
        int pl = r / 12, s12 = r - pl * 12;
        bf16x8 v = *(const bf16x8*)(xgb + (size_t)(n0 + n) * 192 + pl * 96 + s12 * 8);
        *(bf16x8*)(xga + pl * 3328 + n * 104 + s12 * 8) = v;
    }
    {
        int r = tid >> 3, e2 = (tid & 7) * 2;
        *(float2*)(s_s + r * 16 + e2) = *(const float2*)(stock + (size_t)(n0 + r) * 16 + e2);
    }
    __syncthreads();

    f32x16 acc[4] = {};
    const int e0 = w * 4;

    #pragma unroll
    for (int ks = 0; ks < 6; ++ks) {
        bf16x8 Ah = *(const bf16x8*)(xga + o * 104 + ks * 16 + 8 * h);
        bf16x8 Al = *(const bf16x8*)(xga + 3328 + o * 104 + ks * 16 + 8 * h);
        #pragma unroll
        for (int ei = 0; ei < 4; ++ei) {
            bf16x8 Bh = *(const bf16x8*)(wq + (size_t)((e0 + ei) * 6 + ks) * 512 + o * 16 + h * 8);
            acc[ei] = __builtin_amdgcn_mfma_f32_32x32x16_bf16(Ah, Bh, acc[ei], 0, 0, 0);
            acc[ei] = __builtin_amdgcn_mfma_f32_32x32x16_bf16(Al, Bh, acc[ei], 0, 0, 0);
        }
    }

    float pr[16];
    #pragma unroll
    for (int r = 0; r < 16; ++r) pr[r] = 0.f;
    #pragma unroll
    for (int ei = 0; ei < 4; ++ei) {
        const int eg = e0 + ei;
        const float bv = bias[eg * 32 + o];
        #pragma unroll
        for (int r = 0; r < 16; ++r) {
            int node = (r & 3) + 8 * (r >> 2) + 4 * h;
            pr[r] += s_s[node * 16 + eg] * (acc[ei][r] + bv);
        }
    }
    #pragma unroll
    for (int r = 0; r < 16; ++r) {
        int node = (r & 3) + 8 * (r >> 2) + 4 * h;
        ps[w * 1056 + node * 33 + o] = pr[r];
    }
    __syncthreads();
    {
        const int node = tid >> 3, og = (tid & 7) * 4;
        float4 s;
        #pragma unroll
        for (int i = 0; i < 4; ++i) {
            int c = node * 33 + og + i;
            ((float*)&s)[i] = ps[c] + ps[1056 + c] + ps[2112 + c] + ps[3168 + c];
        }
        *(float4*)(out + (size_t)(n0 + node) * 32 + og) = s;
    }
}

extern "C" void kernel_launch(void* const* d_in, const int* in_sizes, int n_in,
                              void* d_out, int out_size, void* d_ws, size_t ws_size,
                              hipStream_t stream) {
    const float* x     = (const float*)d_in[0];
    const float* aemb  = (const float*)d_in[1];
    const float* stock = (const float*)d_in[2];
    const float* Wp    = (const float*)d_in[3];
    const float* bias  = (const float*)d_in[4];
    float* out = (float*)d_out;

    float*  ws  = (float*)d_ws;
    __bf16* es  = (__bf16*)ws;                  // 524288 bf16
    __bf16* vt1 = (__bf16*)(ws + 262144);       // 1048576 bf16 (hi plane used)
    __bf16* vt2 = (__bf16*)(ws + 786432);       // 1048576 bf16 (hi plane used)
    __bf16* xgb = (__bf16*)(ws + 1310720);      // 3145728 bf16
    __bf16* wq  = (__bf16*)(ws + 2883584);      // 49152 bf16 (hi plane)

    prep<<<dim3(536), dim3(256), 0, stream>>>(aemb, x, Wp, es, vt1, xgb, wq);
    apply_mfma<1><<<dim3(512), dim3(256), 0, stream>>>(es, vt1, x, vt2, xgb);
    apply_mfma<2><<<dim3(512), dim3(256), 0, stream>>>(es, vt2, x, vt2, xgb);
    final_mfma<<<dim3(512), dim3(256), 0, stream>>>(xgb, stock, wq, bias, out);
}

// Round 7
// 29.101 us; speedup vs baseline: 4.5344x; 1.1467x over previous
//
#include <hip/hip_runtime.h>
#include <stdint.h>

typedef __bf16 bf16x8 __attribute__((ext_vector_type(8)));
typedef __bf16 bf16x4 __attribute__((ext_vector_type(4)));
typedef float  f32x16 __attribute__((ext_vector_type(16)));

constexpr int kB = 16;
constexpr int kN = 1024;

struct bfhl { __bf16 h, l; };
__device__ __forceinline__ bfhl hilo(float v) {
    bfhl r;
    r.h = (__bf16)v;
    r.l = (__bf16)(v - (float)r.h);
    return r;
}

// m-offset ordering of P fragments: P0[j] holds row (j<4 ? j+4h : j+4+4h),
// P1 the same +16. V fragments must be written in the identical order.
__device__ __forceinline__ int moff(int f, int h, int j) {
    return 16 * f + ((j < 4) ? (4 * h + j) : (4 * h + j + 4));
}

// ---------------------------------------------------------------------------
// Fragment layouts (all bf16, lane = h*32 + (l&31), 8 elems/lane = 16B):
//  esf [b][kt(32)][pl(2)][lane(64)][8] : E_pl[kt*32+(l&31)][8h+j]
//  vtf [b][mt(32)][f(2)][lane(64)][8]  : V_hi[d=(l&31)][mt*32+moff(f,h,j)]
//  xgf [ntile(512)][ks(4)][pl(2)][lane(64)][8] : XG_pl[nt*32+(l&31)][16ks+8h+j]
//  wq  [e][ks(6)][o*16+h*8+j]          : W_hi[16ks+8h+j][o]
// ---------------------------------------------------------------------------

__global__ __launch_bounds__(256) void prep(
    const float* __restrict__ emb, const float* __restrict__ x,
    const float* __restrict__ Wp,
    __bf16* __restrict__ esf, __bf16* __restrict__ vtf1,
    __bf16* __restrict__ xgf, __bf16* __restrict__ wq)
{
    __shared__ float ls[64 * 36];
    const int tid = threadIdx.x;
    const int bid = blockIdx.x;

    if (bid < 256) {
        // emb -> esf fragments. block = batch b, 64 rows.
        const int b = bid >> 4, rg = (bid & 15) << 6;
        const int r = tid >> 2, seg = tid & 3;
        float4 v = *(const float4*)(emb + ((size_t)(b * kN + rg + r) * 16 + seg * 4));
        float f[4] = {v.x, v.y, v.z, v.w};
        bf16x4 hi, lo;
        #pragma unroll
        for (int i = 0; i < 4; ++i) { bfhl t = hilo(f[i]); hi[i] = t.h; lo[i] = t.l; }
        const int kt = ((bid & 15) << 1) + (r >> 5);
        const int lane = ((seg >> 1) << 5) + (r & 31);
        const int j0 = (seg & 1) << 2;
        __bf16* base = esf + ((size_t)(b * 32 + kt) * 2) * 512 + lane * 8 + j0;
        *(bf16x4*)base         = hi;
        *(bf16x4*)(base + 512) = lo;
    } else if (bid < 512) {
        // x -> vtf1 fragments + xgf ks=0,1. block = batch b, 64 rows (2 tiles).
        const int bb = bid - 256;
        const int b = bb >> 4, n0 = (bb & 15) << 6;
        const float* sB = x + ((size_t)b * kN + n0) * 32;
        #pragma unroll
        for (int it = 0; it < 2; ++it) {
            int f = it * 256 + tid;
            int row = f >> 3, q8 = f & 7;
            float4 v = *(const float4*)(sB + (size_t)row * 32 + q8 * 4);
            *(float4*)(&ls[row * 36 + q8 * 4]) = v;
        }
        __syncthreads();
        {   // vtf1: (mt, f, lane)
            const int mt = tid >> 7, fr = (tid >> 6) & 1, l = tid & 63;
            const int d = l & 31, h = l >> 5;
            bf16x8 ov;
            #pragma unroll
            for (int j = 0; j < 8; ++j)
                ov[j] = (__bf16)ls[(mt * 32 + moff(fr, h, j)) * 36 + d];
            *(bf16x8*)(vtf1 + ((size_t)(b * 32 + (n0 >> 5) + mt) * 2 + fr) * 512 + l * 8) = ov;
        }
        #pragma unroll
        for (int mt = 0; mt < 2; ++mt) {  // xgf ks 0,1 (XG = x)
            const int ks = tid >> 7, pl = (tid >> 6) & 1, l = tid & 63;
            const int node = l & 31, h = l >> 5;
            const float* rp = &ls[(mt * 32 + node) * 36 + ks * 16 + 8 * h];
            float4 u0 = *(const float4*)rp;
            float4 u1 = *(const float4*)(rp + 4);
            float u[8] = {u0.x, u0.y, u0.z, u0.w, u1.x, u1.y, u1.z, u1.w};
            bf16x8 ov;
            #pragma unroll
            for (int j = 0; j < 8; ++j) {
                bfhl t = hilo(u[j]);
                ov[j] = pl ? t.l : t.h;
            }
            const int ntile = b * 32 + (n0 >> 5) + mt;
            *(bf16x8*)(xgf + ((size_t)(ntile * 4 + ks) * 2 + pl) * 512 + l * 8) = ov;
        }
    } else {
        int idx = (bid - 512) * 256 + tid;   // (e, ks, o, h)
        if (idx < 6144) {
            int e = idx / 384, rem = idx - e * 384;
            int ks = rem / 64, r2 = rem - ks * 64;
            int o = r2 >> 1, h = r2 & 1;
            int ki0 = ks * 16 + h * 8;
            bf16x8 hi;
            #pragma unroll
            for (int j = 0; j < 8; ++j)
                hi[j] = (__bf16)Wp[(size_t)e * 3072 + (size_t)(ki0 + j) * 32 + o];
            *(bf16x8*)(wq + (size_t)(e * 6 + ks) * 512 + o * 16 + h * 8) = hi;
        }
    }
}

// ---------------------------------------------------------------------------
// apply_mfma<STAGE>: Y = softmax_row(relu(E E^T)) @ V, zero-LDS main loop.
// STAGE 1: V = vtf1(x); epilogue writes vtf2 + xgf ks=2,3 (y1).
// STAGE 2: V = vtf2(y1); epilogue = FUSED final GEMM -> out.
// grid 512 (= ntile), 256 threads (4 waves, wave w owns kt = it*4+w).
// ---------------------------------------------------------------------------
template<int STAGE>
__global__ __launch_bounds__(256, 2) void apply_mfma(
    const __bf16* __restrict__ esf,
    const __bf16* __restrict__ vtin,
    const float*  __restrict__ x,      // stage 2
    __bf16* __restrict__ vtout,        // stage 1
    __bf16* __restrict__ xgf,          // stage 1: write ks2,3 ; stage 2: read ks0..3
    const __bf16* __restrict__ wq,     // stage 2
    const float*  __restrict__ stock,  // stage 2
    const float*  __restrict__ bias,   // stage 2
    float* __restrict__ out)           // stage 2
{
    __shared__ alignas(16) char smem[24576];
    float*  ps  = (float*)smem;                    // 4224 f32
    float*  Ls  = (float*)(smem + 16896);          // 128 f32
    float*  yb  = (float*)(smem + 17408);          // stage1: 32*36 f32
    __bf16* xg2 = (__bf16*)(smem + 17408);         // stage2: [2][32][36] bf16
    float*  s_s = (float*)(smem + 22016);          // stage2: 32*16 f32

    const int tid = threadIdx.x;
    const int w = tid >> 6, l = tid & 63;
    const int q = l & 31, h = l >> 5;
    const int b = blockIdx.x >> 5, q0 = (blockIdx.x & 31) << 5;
    const int ntile = blockIdx.x;

    const __bf16* esfB = esf + (size_t)b * 32768;
    const __bf16* vtfB = vtin + (size_t)b * 32768;

    if (STAGE == 2) {   // stage stock early (read after first sync)
        int r = tid >> 3, e2 = (tid & 7) * 2;
        *(float2*)(s_s + r * 16 + e2) =
            *(const float2*)(stock + (size_t)(b * kN + q0 + r) * 16 + e2);
    }

    // Q-side B-fragments
    bf16x8 bhi = *(const bf16x8*)(esfB + ((size_t)(q0 >> 5) * 2) * 512 + l * 8);
    bf16x8 blo = *(const bf16x8*)(esfB + ((size_t)(q0 >> 5) * 2 + 1) * 512 + l * 8);

    f32x16 acc = {};
    float Lp = 0.f;

    #pragma unroll 2
    for (int it = 0; it < 8; ++it) {
        const int kt = it * 4 + w;
        bf16x8 ahi = *(const bf16x8*)(esfB + ((size_t)kt * 2) * 512 + l * 8);
        bf16x8 alo = *(const bf16x8*)(esfB + ((size_t)kt * 2 + 1) * 512 + l * 8);
        bf16x8 A0  = *(const bf16x8*)(vtfB + ((size_t)kt * 2) * 512 + l * 8);
        bf16x8 A1  = *(const bf16x8*)(vtfB + ((size_t)kt * 2 + 1) * 512 + l * 8);

        f32x16 S = {};
        S = __builtin_amdgcn_mfma_f32_32x32x16_bf16(ahi, bhi, S, 0, 0, 0);
        S = __builtin_amdgcn_mfma_f32_32x32x16_bf16(ahi, blo, S, 0, 0, 0);
        S = __builtin_amdgcn_mfma_f32_32x32x16_bf16(alo, bhi, S, 0, 0, 0);

        float p[16];
        #pragma unroll
        for (int r = 0; r < 16; ++r) {
            p[r] = __expf(fmaxf(S[r], 0.f));
            Lp += p[r];
        }
        bf16x8 P0, P1;
        #pragma unroll
        for (int j = 0; j < 8; ++j) { P0[j] = (__bf16)p[j]; P1[j] = (__bf16)p[8 + j]; }

        acc = __builtin_amdgcn_mfma_f32_32x32x16_bf16(A0, P0, acc, 0, 0, 0);
        acc = __builtin_amdgcn_mfma_f32_32x32x16_bf16(A1, P1, acc, 0, 0, 0);
    }

    // merge wave partials: ps[w][d][q], Ls[w][q]
    Lp += __shfl_xor(Lp, 32);
    #pragma unroll
    for (int r = 0; r < 16; ++r) {
        int d = (r & 3) + 8 * (r >> 2) + 4 * h;
        ps[w * 1056 + d * 33 + q] = acc[r];
    }
    if (l < 32) Ls[w * 32 + l] = Lp;
    __syncthreads();

    // thread (qq, dg): node qq, dims dg*4..+3
    const int qq = tid >> 3, dg = tid & 7;
    const float iL = 1.f / (Ls[qq] + Ls[32 + qq] + Ls[64 + qq] + Ls[96 + qq]);
    float yv[4];
    #pragma unroll
    for (int i = 0; i < 4; ++i) {
        int d = dg * 4 + i;
        yv[i] = (ps[d * 33 + qq] + ps[1056 + d * 33 + qq] +
                 ps[2112 + d * 33 + qq] + ps[3168 + d * 33 + qq]) * iL;
    }

    if (STAGE == 1) {
        #pragma unroll
        for (int i = 0; i < 4; ++i) yb[qq * 36 + dg * 4 + i] = yv[i];
        __syncthreads();
        if (tid < 128) {   // vtf2 fragments
            const int fr = tid >> 6, l2 = tid & 63;
            const int d = l2 & 31, h2 = l2 >> 5;
            bf16x8 ov;
            #pragma unroll
            for (int j = 0; j < 8; ++j)
                ov[j] = (__bf16)yb[moff(fr, h2, j) * 36 + d];
            *(bf16x8*)(vtout + ((size_t)(b * 32 + (q0 >> 5)) * 2 + fr) * 512 + l2 * 8) = ov;
        }
        {   // xgf ks 2,3 (XG = y1)
            const int ks2 = tid >> 7, pl = (tid >> 6) & 1, l2 = tid & 63;
            const int node = l2 & 31, h2 = l2 >> 5;
            const float* rp = &yb[node * 36 + ks2 * 16 + 8 * h2];
            float4 u0 = *(const float4*)rp;
            float4 u1 = *(const float4*)(rp + 4);
            float u[8] = {u0.x, u0.y, u0.z, u0.w, u1.x, u1.y, u1.z, u1.w};
            bf16x8 ov;
            #pragma unroll
            for (int j = 0; j < 8; ++j) {
                bfhl t = hilo(u[j]);
                ov[j] = pl ? t.l : t.h;
            }
            *(bf16x8*)(xgf + ((size_t)(ntile * 4 + 2 + ks2) * 2 + pl) * 512 + l2 * 8) = ov;
        }
    } else {
        // ---- fused final: xg2 = 2*y2 - x (k 64..95), then out ----
        {
            float4 xv = *(const float4*)(x + (size_t)(b * kN + q0 + qq) * 32 + dg * 4);
            float g[4] = {2.f * yv[0] - xv.x, 2.f * yv[1] - xv.y,
                          2.f * yv[2] - xv.z, 2.f * yv[3] - xv.w};
            bf16x4 hi, lo;
            #pragma unroll
            for (int i = 0; i < 4; ++i) { bfhl t = hilo(g[i]); hi[i] = t.h; lo[i] = t.l; }
            *(bf16x4*)(xg2 + qq * 36 + dg * 4)        = hi;
            *(bf16x4*)(xg2 + 1152 + qq * 36 + dg * 4) = lo;
        }
        __syncthreads();

        f32x16 acc2[4] = {};
        const int e0 = w * 4;
        const int o = q;   // l&31: A-side node index == B/D-side o index

        #pragma unroll
        for (int ks = 0; ks < 6; ++ks) {
            bf16x8 Ah, Al;
            if (ks < 4) {
                Ah = *(const bf16x8*)(xgf + ((size_t)(ntile * 4 + ks) * 2) * 512 + l * 8);
                Al = *(const bf16x8*)(xgf + ((size_t)(ntile * 4 + ks) * 2 + 1) * 512 + l * 8);
            } else {
                const int base = o * 36 + (ks - 4) * 16 + 8 * h;
                bf16x4 a0 = *(const bf16x4*)(xg2 + base);
                bf16x4 a1 = *(const bf16x4*)(xg2 + base + 4);
                bf16x4 b0 = *(const bf16x4*)(xg2 + 1152 + base);
                bf16x4 b1 = *(const bf16x4*)(xg2 + 1152 + base + 4);
                #pragma unroll
                for (int j = 0; j < 4; ++j) {
                    Ah[j] = a0[j]; Ah[4 + j] = a1[j];
                    Al[j] = b0[j]; Al[4 + j] = b1[j];
                }
            }
            #pragma unroll
            for (int ei = 0; ei < 4; ++ei) {
                bf16x8 Bh = *(const bf16x8*)(wq + (size_t)((e0 + ei) * 6 + ks) * 512 + o * 16 + h * 8);
                acc2[ei] = __builtin_amdgcn_mfma_f32_32x32x16_bf16(Ah, Bh, acc2[ei], 0, 0, 0);
                acc2[ei] = __builtin_amdgcn_mfma_f32_32x32x16_bf16(Al, Bh, acc2[ei], 0, 0, 0);
            }
        }

        float pr[16];
        #pragma unroll
        for (int r = 0; r < 16; ++r) pr[r] = 0.f;
        #pragma unroll
        for (int ei = 0; ei < 4; ++ei) {
            const int eg = e0 + ei;
            const float bv = bias[eg * 32 + o];
            #pragma unroll
            for (int r = 0; r < 16; ++r) {
                int node = (r & 3) + 8 * (r >> 2) + 4 * h;
                pr[r] += s_s[node * 16 + eg] * (acc2[ei][r] + bv);
            }
        }
        #pragma unroll
        for (int r = 0; r < 16; ++r) {
            int node = (r & 3) + 8 * (r >> 2) + 4 * h;
            ps[w * 1056 + node * 33 + o] = pr[r];
        }
        __syncthreads();
        {
            const int node = tid >> 3, og = (tid & 7) * 4;
            float4 s;
            #pragma unroll
            for (int i = 0; i < 4; ++i) {
                int c = node * 33 + og + i;
                ((float*)&s)[i] = ps[c] + ps[1056 + c] + ps[2112 + c] + ps[3168 + c];
            }
            *(float4*)(out + (size_t)(b * kN + q0 + node) * 32 + og) = s;
        }
    }
}

extern "C" void kernel_launch(void* const* d_in, const int* in_sizes, int n_in,
                              void* d_out, int out_size, void* d_ws, size_t ws_size,
                              hipStream_t stream) {
    const float* x     = (const float*)d_in[0];
    const float* aemb  = (const float*)d_in[1];
    const float* stock = (const float*)d_in[2];
    const float* Wp    = (const float*)d_in[3];
    const float* bias  = (const float*)d_in[4];
    float* out = (float*)d_out;

    __bf16* wsb  = (__bf16*)d_ws;
    __bf16* esf  = wsb;               // 524288
    __bf16* vtf1 = wsb + 524288;      // 524288
    __bf16* vtf2 = wsb + 1048576;     // 524288
    __bf16* xgf  = wsb + 1572864;     // 2097152
    __bf16* wq   = wsb + 3670016;     // 49152

    prep<<<dim3(536), dim3(256), 0, stream>>>(aemb, x, Wp, esf, vtf1, xgf, wq);
    apply_mfma<1><<<dim3(512), dim3(256), 0, stream>>>(
        esf, vtf1, x, vtf2, xgf, wq, stock, bias, out);
    apply_mfma<2><<<dim3(512), dim3(256), 0, stream>>>(
        esf, vtf2, x, nullptr, xgf, wq, stock, bias, out);
}